// Round 12
// baseline (340.315 us; speedup 1.0000x reference)
//
#include <hip/hip_runtime.h>
#include <hip/hip_bf16.h>

// DGCF forward, MI355X. f32 in/out.
// R11-R22: padded-bucket CSR build, fused walk+scores+softmax+D (wave/node,
// deg-adaptive NJ chunks), bf16 tables, dot2bf, pre-scaled G=x*d, merged
// per-edge record svA = {sv bf16 | A f16}.
// R23: combined node record XT[n] = [G row | te row] (256 B). One base addr
// per edge feeds BOTH gathers (te = +128 B folded into the load offset);
// same-record gathers share the DRAM page / L2 line-pair. XT_A/XT_B ping-pong
// with te halves duplicated at init (te_a) and written in it1 (te_b).
#define NUSER 50000
#define NITEM 50000
#define NN    100000          // NUSER+NITEM
#define NNZ_  1000000
#define DIM_  64
#define NBLK  391             // ceil_div(NN,256) == bucket count
#define EPB   2560            // edges per scatter block (391*2560 >= NNZ)
#define BINC  4096            // per-bucket window capacity (mean 2560, +30 sigma)
#define NPAD  (NBLK * BINC)   // padded edge-index space (1,601,536)

#define FL_SVC    1   // walk weights uniform (it0; constant cancels in norm)
#define FL_SC     2   // fused scores: dot(fn, te[tail]) -> A -> softmax -> svA
#define FL_NEXT   8   // write ego_next(raw) + XT te-half + XT G-half (from fn)
#define FL_FIN    16  // out = (out + X_row + fn) / 3
#define FL_ACONST 32  // scores: A_old == 1 (skip record load if also FL_SVC)
#define FL_GN     128 // build XT G-half = X_row * d  (X loaded, d from scores)

static inline int ceil_div(int a, int b) { return (a + b - 1) / b; }

static __device__ inline float bf2f(unsigned short u) {
    return __uint_as_float(((unsigned int)u) << 16);
}
static __device__ inline unsigned short f2bf(float f) {
    unsigned int x = __float_as_uint(f);
    x += 0x7fffu + ((x >> 16) & 1u);
    return (unsigned short)(x >> 16);
}
static __device__ inline unsigned short f2h(float f) {
    _Float16 h = (_Float16)f;
    return __builtin_bit_cast(unsigned short, h);
}
static __device__ inline float h2f(unsigned short u) {
    return (float)__builtin_bit_cast(_Float16, u);
}

// packed bf16x2 dot: c += a.lo*b.lo + a.hi*b.hi (hw v_dot2_f32_bf16 if present)
#if __has_builtin(__builtin_amdgcn_fdot2_f32_bf16)
typedef __bf16 bf16x2_t __attribute__((ext_vector_type(2)));
static __device__ inline float dot2bf(unsigned int a, unsigned int b, float c) {
    return __builtin_amdgcn_fdot2_f32_bf16(__builtin_bit_cast(bf16x2_t, a),
                                           __builtin_bit_cast(bf16x2_t, b), c, false);
}
#else
static __device__ inline float dot2bf(unsigned int a, unsigned int b, float c) {
    return c + bf2f((unsigned short)(a & 0xffffu)) * bf2f((unsigned short)(b & 0xffffu))
             + bf2f((unsigned short)(a >> 16)) * bf2f((unsigned short)(b >> 16));
}
#endif

// ---- padded-bucket CSR build (once per launch) ----
__global__ void k_binscat(const int* __restrict__ head, const int* __restrict__ tail,
                          int* __restrict__ cursor, int* __restrict__ bin) {
    __shared__ int cnt[NBLK];
    __shared__ int chunk[NBLK];
    int tid = threadIdx.x;
    for (int i = tid; i < NBLK; i += 256) cnt[i] = 0;
    __syncthreads();
    int e0 = blockIdx.x * EPB;
    int e1 = min(e0 + EPB, NNZ_);
    for (int e = e0 + tid; e < e1; e += 256)
        atomicAdd(&cnt[head[e] >> 8], 1);
    __syncthreads();
    for (int i = tid; i < NBLK; i += 256) {
        chunk[i] = cnt[i] ? (i * BINC + atomicAdd(&cursor[i], cnt[i])) : 0;
        cnt[i] = 0;   // reuse as local cursor
    }
    __syncthreads();
    for (int e = e0 + tid; e < e1; e += 256) {
        int h = head[e], t = tail[e];
        int b = h >> 8;
        int off = atomicAdd(&cnt[b], 1);
        bin[chunk[b] + off] = t | ((h & 255) << 20);   // t < 2^17, hl < 2^8
    }
}

__global__ void k_bucket(const int* __restrict__ bin, const int* __restrict__ cursor,
                         int2* __restrict__ row_se, float4* __restrict__ d4a,
                         int* __restrict__ csr_tail) {
    __shared__ int deg[256];
    __shared__ int sh[256];
    __shared__ int cur[256];
    int tid = threadIdx.x;
    int b = blockIdx.x;
    int n0 = b << 8;
    int e0 = b * BINC, e1 = e0 + cursor[b];
    deg[tid] = 0;
    __syncthreads();
    for (int e = e0 + tid; e < e1; e += 256)
        atomicAdd(&deg[bin[e] >> 20], 1);
    __syncthreads();
    int myDeg = deg[tid];
    sh[tid] = myDeg;
    __syncthreads();
    for (int off = 1; off < 256; off <<= 1) {
        int u = 0;
        if (tid >= off) u = sh[tid - off];
        __syncthreads();
        sh[tid] += u;
        __syncthreads();
    }
    int loff = sh[tid] - myDeg;   // exclusive local offset
    int start = b * BINC + loff;  // csr window shares the BINC stride
    int n = n0 + tid;
    if (n < NN) {
        row_se[n] = make_int2(start, start + myDeg);
        float dd = (myDeg > 0) ? 2.0f / sqrtf((float)myDeg) : 0.0f;
        d4a[n] = make_float4(dd, dd, dd, dd);
    }
    cur[tid] = start;
    __syncthreads();
    for (int e = e0 + tid; e < e1; e += 256) {
        int p = bin[e];
        int pos = atomicAdd(&cur[p >> 20], 1);
        csr_tail[pos] = p & 0xFFFFF;
    }
}

// ego = raw bf16; XT_A = [G0 = ego*d0 | te_a]; XT_B te-half = te_a; out = ego.
// Runs AFTER the CSR build (reads d4a for the G0 seed).
__global__ void k_init(const float* __restrict__ eu, const float* __restrict__ ei,
                       const float* __restrict__ d4a,   // viewed as float[NN*4]
                       unsigned short* __restrict__ ego,
                       unsigned short* __restrict__ XTa, unsigned short* __restrict__ XTb,
                       float* __restrict__ out) {
    int i = blockIdx.x * 256 + threadIdx.x;
    if (i >= NN * DIM_) return;
    float v = (i < NUSER * DIM_) ? eu[i] : ei[i - NUSER * DIM_];
    out[i] = v;
    ego[i] = f2bf(v);
    int xi = i + (i & ~63);          // (i>>6)*128 + (i&63)
    XTa[xi] = f2bf(v * d4a[i >> 4]); // G0 half
    float s = v * v;
    s += __shfl_xor(s, 1); s += __shfl_xor(s, 2);
    s += __shfl_xor(s, 4); s += __shfl_xor(s, 8);
    float nrm = v / fmaxf(sqrtf(s), 1e-12f);
    float ex = __expf(2.0f * nrm);
    unsigned short tb = f2bf((ex - 1.0f) / (ex + 1.0f));
    XTa[xi + 64] = tb;               // te_a into both XTs
    XTb[xi + 64] = tb;
}

// ---- fused walk + scores body, NJ = chunk depth in 4-edge steps ----
// lane = 16*q + l: q = edge slot (0..3), l = dim quad (dims 4l..4l+3), f = l>>2.
// Node record XT[t]: shorts [0..63] = G (pre-scaled x*d), [64..127] = te.
// One base addr per edge; te load = base + 128 B (offset immediate).
template<int FLAGS, int NJ>
static __device__ __forceinline__ void iter_body(
    int n, int lane, int q, int l, int f, int r0, int r1,
    unsigned int* __restrict__ svA,
    const unsigned short* __restrict__ XT,
    const int* __restrict__ csr_tail,
    float* __restrict__ out,
    const unsigned short* __restrict__ X,   // raw row source (GN / FIN)
    unsigned short* __restrict__ GnXT,      // next XT (G-half; NEXT also te-half)
    unsigned short* __restrict__ egon)      // raw fn store (NEXT)
{
    constexpr bool needRec = !(FLAGS & FL_SVC) || ((FLAGS & FL_SC) && !(FLAGS & FL_ACONST));
    float ax = 0.f, ay = 0.f, az = 0.f, aw = 0.f;

    // ---- chunk 0: edges r0+q+4j, j=0..NJ-1 (te cached for scores phase) ----
    int ct[NJ]; float cw[NJ]; unsigned int cr[NJ]; uint2 cv[NJ];
    int eb = r0 + q;
#pragma unroll
    for (int j = 0; j < NJ; ++j) {
        int i = eb + 4 * j;
        bool v = (i < r1);
        int ic = v ? i : r0;
        int t = csr_tail[ic];
        ct[j] = v ? t : 0;            // padding holes are uninitialized
        if (needRec) cr[j] = svA[ic * 4 + f];
        float w;
        if (FLAGS & FL_SVC) w = 1.0f;
        else w = bf2f((unsigned short)(cr[j] & 0xffffu));
        cw[j] = v ? w : 0.f;
    }
#pragma unroll
    for (int j = 0; j < NJ; ++j) {
        if (FLAGS & FL_SC)
            cv[j] = *(const uint2*)(XT + ct[j] * 128 + 64 + 4 * l);
    }
#pragma unroll
    for (int j = 0; j < NJ; ++j) {
        ushort4 u = *(const ushort4*)(XT + ct[j] * 128 + 4 * l);
        ax += cw[j] * bf2f(u.x); ay += cw[j] * bf2f(u.y);
        az += cw[j] * bf2f(u.z); aw += cw[j] * bf2f(u.w);
    }

    // ---- remainder chunks (deg > 16), only reachable in the NJ==4 arm ----
    if (NJ == 4) {
        for (int base = r0 + 16; base < r1; base += 16) {
            int tj[4]; float wj[4];
#pragma unroll
            for (int j = 0; j < 4; ++j) {
                int i = base + q + 4 * j;
                bool v = (i < r1);
                int ic = v ? i : r0;
                int t = csr_tail[ic];
                tj[j] = v ? t : 0;
                float w;
                if (FLAGS & FL_SVC) w = 1.0f;
                else w = bf2f((unsigned short)(svA[ic * 4 + f] & 0xffffu));
                wj[j] = v ? w : 0.f;
            }
#pragma unroll
            for (int j = 0; j < 4; ++j) {
                ushort4 u = *(const ushort4*)(XT + tj[j] * 128 + 4 * l);
                ax += wj[j] * bf2f(u.x); ay += wj[j] * bf2f(u.y);
                az += wj[j] * bf2f(u.z); aw += wj[j] * bf2f(u.w);
            }
        }
    }

    // reduce over edge slots -> each lane holds full sums for its dim quad
    ax += __shfl_xor(ax, 16); ax += __shfl_xor(ax, 32);
    ay += __shfl_xor(ay, 16); ay += __shfl_xor(ay, 32);
    az += __shfl_xor(az, 16); az += __shfl_xor(az, 32);
    aw += __shfl_xor(aw, 16); aw += __shfl_xor(aw, 32);

    // l2 norm over the 16-dim factor chunk (quad layout: reduce over l&3)
    float s = ax * ax + ay * ay + az * az + aw * aw;
    s += __shfl_xor(s, 1); s += __shfl_xor(s, 2);
    float inv = 1.0f / fmaxf(sqrtf(s), 1e-12f);
    float fx = ax * inv, fy = ay * inv, fz = az * inv, fw = aw * inv;

    float y = 0.f;
    if (FLAGS & (FL_NEXT | FL_FIN)) {
        // redistribute: lane p takes dim p (= component p&3 of lane p>>2's quad)
        int src = lane >> 2;
        float t0r = __shfl(fx, src), t1r = __shfl(fy, src);
        float t2r = __shfl(fz, src), t3r = __shfl(fw, src);
        y = (lane & 2) ? ((lane & 1) ? t3r : t2r) : ((lane & 1) ? t1r : t0r);
        int base = n * 64 + lane;
        if (FLAGS & FL_FIN) {
            // out holds init; X row n holds bf16 fn1 -> 3-term mean
            out[base] = (out[base] + bf2f(X[base]) + y) * (1.0f / 3.0f);
        }
        if (FLAGS & FL_NEXT) {
            egon[base] = f2bf(y);
            float e2 = __expf(2.0f * y);
            GnXT[n * 128 + 64 + lane] = f2bf((e2 - 1.0f) / (e2 + 1.0f));  // te-half
        }
    }

    float accs = 0.f;   // rowsum of svals for this lane's factor f
    if (FLAGS & FL_SC) {
        // pack fn once per node: lane's 4 dims -> two bf16x2 dwords
        unsigned int p01 = ((unsigned int)f2bf(fy) << 16) | f2bf(fx);
        unsigned int p23 = ((unsigned int)f2bf(fw) << 16) | f2bf(fz);
        // cached chunk 0: pure register compute
#pragma unroll
        for (int j = 0; j < NJ; ++j) {
            int i = eb + 4 * j;
            bool v = (i < r1);
            float dot = dot2bf(cv[j].y, p23, dot2bf(cv[j].x, p01, 0.0f));
            dot += __shfl_xor(dot, 1); dot += __shfl_xor(dot, 2);
            float a = (FLAGS & FL_ACONST) ? 1.0f : h2f((unsigned short)(cr[j] >> 16));
            a += dot;
            float ex = __expf(a);
            float sum = ex;
            sum += __shfl_xor(sum, 4); sum += __shfl_xor(sum, 8);
            float sv = ex / sum;
            if (v && (l & 3) == 0)
                svA[i * 4 + f] = (unsigned int)f2bf(sv) | ((unsigned int)f2h(a) << 16);
            accs += v ? sv : 0.f;
        }
        // remainder chunks: pipelined re-gather of tails/records -> te
        if (NJ == 4) {
            for (int base = r0 + 16; base < r1; base += 16) {
                int tj[4]; float aj[4]; uint2 vj[4];
#pragma unroll
                for (int j = 0; j < 4; ++j) {
                    int i = base + q + 4 * j;
                    bool v = (i < r1);
                    int ic = v ? i : r0;
                    int t = csr_tail[ic];
                    tj[j] = v ? t : 0;
                    if (!(FLAGS & FL_ACONST))
                        aj[j] = h2f((unsigned short)(svA[ic * 4 + f] >> 16));
                }
#pragma unroll
                for (int j = 0; j < 4; ++j)
                    vj[j] = *(const uint2*)(XT + tj[j] * 128 + 64 + 4 * l);
#pragma unroll
                for (int j = 0; j < 4; ++j) {
                    int i = base + q + 4 * j;
                    bool v = (i < r1);
                    float dot = dot2bf(vj[j].y, p23, dot2bf(vj[j].x, p01, 0.0f));
                    dot += __shfl_xor(dot, 1); dot += __shfl_xor(dot, 2);
                    float a = (FLAGS & FL_ACONST) ? 1.0f : aj[j];
                    a += dot;
                    float ex = __expf(a);
                    float sum = ex;
                    sum += __shfl_xor(sum, 4); sum += __shfl_xor(sum, 8);
                    float sv = ex / sum;
                    if (v && (l & 3) == 0)
                        svA[i * 4 + f] = (unsigned int)f2bf(sv) | ((unsigned int)f2h(a) << 16);
                    accs += v ? sv : 0.f;
                }
            }
        }
        // reduce over edge slots q (value replicated over the l&3 dups)
        accs += __shfl_xor(accs, 16); accs += __shfl_xor(accs, 32);
    }

    if (FLAGS & (FL_GN | FL_NEXT)) {
        // d for this lane's OUTPUT factor (dim = lane, factor = lane>>4):
        // accs for factor g lives on lane 4*g (and dups).
        float av = __shfl(accs, (lane >> 4) << 2);
        float d = (av > 0.f) ? 1.0f / sqrtf(fmaxf(av, 1e-12f)) : 0.f;
        float src = (FLAGS & FL_NEXT) ? y : bf2f(X[n * 64 + lane]);
        GnXT[n * 128 + lane] = f2bf(src * d);   // G-half
    }
}

// dispatcher: one wave per node; deg is wave-uniform (SGPR) -> scalar branch
template<int FLAGS>
__global__ void k_iter(unsigned int* __restrict__ svA,
                       const unsigned short* __restrict__ XT,
                       const int2* __restrict__ row_se, const int* __restrict__ csr_tail,
                       float* __restrict__ out,
                       const unsigned short* __restrict__ X,
                       unsigned short* __restrict__ GnXT,
                       unsigned short* __restrict__ egon) {
    int n = (blockIdx.x * 256 + threadIdx.x) >> 6;
    if (n >= NN) return;
    int lane = threadIdx.x & 63;
    int q = lane >> 4;
    int l = lane & 15;
    int f = l >> 2;
    int2 se = row_se[n];
    int r0 = __builtin_amdgcn_readfirstlane(se.x);
    int r1 = __builtin_amdgcn_readfirstlane(se.y);
    int deg = r1 - r0;
    if (deg <= 8) {
        if (deg <= 4)
            iter_body<FLAGS, 1>(n, lane, q, l, f, r0, r1, svA, XT,
                                csr_tail, out, X, GnXT, egon);
        else
            iter_body<FLAGS, 2>(n, lane, q, l, f, r0, r1, svA, XT,
                                csr_tail, out, X, GnXT, egon);
    } else {
        if (deg <= 12)
            iter_body<FLAGS, 3>(n, lane, q, l, f, r0, r1, svA, XT,
                                csr_tail, out, X, GnXT, egon);
        else
            iter_body<FLAGS, 4>(n, lane, q, l, f, r0, r1, svA, XT,
                                csr_tail, out, X, GnXT, egon);
    }
}

extern "C" void kernel_launch(void* const* d_in, const int* in_sizes, int n_in,
                              void* d_out, int out_size, void* d_ws, size_t ws_size,
                              hipStream_t stream) {
    const float* eu = (const float*)d_in[0];
    const float* ei = (const float*)d_in[1];
    const int* head = (const int*)d_in[2];
    const int* tail = (const int*)d_in[3];
    float* out = (float*)d_out;   // holds init until it3's 3-term mean (FL_FIN)

    // workspace layout — ~111 MB (16B-aligned first).
    // XT_A: [G0|te_a] -> [G2|te_b] (it1 epilogue). XT_B: [G1|te_a] -> [G3|..].
    // bin (6.4 MB) aliases svA (bin dead after k_bucket; svA written in it0).
    unsigned int* svA = (unsigned int*)d_ws;                // 25.6 MB (NPAD*4)
    float* d4a = (float*)(svA + (size_t)NPAD * 4);          // 1.6 MB (it0 seed only)
    unsigned short* ego_a = (unsigned short*)(d4a + (size_t)NN * 4);  // 12.8 MB (raw)
    unsigned short* ego_b = ego_a + (size_t)NN * DIM_;      // 12.8 MB (raw fn1)
    unsigned short* XT_A  = ego_b + (size_t)NN * DIM_;      // 25.6 MB
    unsigned short* XT_B  = XT_A + (size_t)NN * 128;        // 25.6 MB
    int* csr_tail = (int*)(XT_B + (size_t)NN * 128);        // 6.4 MB (NPAD)
    int2* row_se = (int2*)(csr_tail + (size_t)NPAD);        // 0.8 MB
    int* cursor = (int*)(row_se + NN);                      // NBLK
    int* bin = (int*)svA;                                   // 6.4 MB alias

    const int node_blocks = ceil_div(NN * DIM_, 256);      // 25000
    const int wave_blocks = ceil_div(NN * 64, 256);        // 25000

    // padded-bucket CSR build + d0 = 2/sqrt(deg) seed (rowsum0 = 0.25*deg)
    hipMemsetAsync(cursor, 0, NBLK * sizeof(int), stream);
    k_binscat<<<NBLK, 256, 0, stream>>>(head, tail, cursor, bin);
    k_bucket<<<NBLK, 256, 0, stream>>>(bin, cursor, row_se, (float4*)d4a, csr_tail);

    // init AFTER csr build: ego_a raw; XT_A = [G0|te_a]; XT_B te-half = te_a.
    k_init<<<node_blocks, 256, 0, stream>>>(eu, ei, d4a, ego_a, XT_A, XT_B, out);

    // it0: walk XT_A (uniform weights cancel in norm); scores vs te_a (XT_A):
    // A1 = 1 + s0, svals_1 -> svA; epilogue G1 = ego_a*d1 -> XT_B G-half.
    k_iter<FL_SVC | FL_SC | FL_ACONST | FL_GN><<<wave_blocks, 256, 0, stream>>>(
        svA, XT_A, row_se, csr_tail, out, ego_a, XT_B, ego_b);

    // it1: walk XT_B with svals_1; scores vs te_a (XT_B); fn1 -> ego_b raw;
    // epilogue writes XT_A = [G2 = fn1*d2 | te_b = tanh(fn1)].
    k_iter<FL_SC | FL_NEXT><<<wave_blocks, 256, 0, stream>>>(
        svA, XT_B, row_se, csr_tail, out, ego_a, XT_A, ego_b);

    // it2: walk XT_A with svals_2; scores vs te_b (XT_A): svals_3 -> svA;
    // epilogue G3 = ego_b*d3 -> XT_B G-half (te-half stale, unused).
    k_iter<FL_SC | FL_GN><<<wave_blocks, 256, 0, stream>>>(
        svA, XT_A, row_se, csr_tail, out, ego_b, XT_B, ego_b);

    // it3: walk XT_B G-half with svals_3; no scores; out = (init+fn1+fn3)/3.
    k_iter<FL_FIN><<<wave_blocks, 256, 0, stream>>>(
        svA, XT_B, row_se, csr_tail, out, ego_b, XT_A, ego_b);
}

// Round 13
// 322.116 us; speedup vs baseline: 1.0565x; 1.0565x over previous
//
#include <hip/hip_runtime.h>
#include <hip/hip_bf16.h>

// DGCF forward, MI355X. f32 in/out.
// R11-R22: padded-bucket CSR build, fused walk+scores+softmax+D, bf16 tables,
// dot2bf, pre-scaled G=x*d, merged per-edge record svA = {sv bf16 | A f16}.
// R23 (reverted): combined XT record regressed (no request-count change).
// R24: 8 lanes per edge slot (lane = 8q+l8; lane owns 8 dims via ONE uint4
// 16 B load) -> gather requests per edge HALVE for both G and te (R15 showed
// the random-gather path is request-rate-bound: 256B-rows hit 3.87 TB/s vs
// 128B-rows 2.38). 8 edge slots/chunk doubles MLP. Reduces: pair (norm),
// xor2/4 (factor softmax), xor8/16/32 (q) — all group-local.
#define NUSER 50000
#define NITEM 50000
#define NN    100000          // NUSER+NITEM
#define NNZ_  1000000
#define DIM_  64
#define NBLK  391             // ceil_div(NN,256) == bucket count
#define EPB   2560            // edges per scatter block (391*2560 >= NNZ)
#define BINC  4096            // per-bucket window capacity (mean 2560, +30 sigma)
#define NPAD  (NBLK * BINC)   // padded edge-index space (1,601,536)

#define FL_SVC    1   // walk weights uniform (it0; constant cancels in norm)
#define FL_SC     2   // fused scores: dot(fn, te[tail]) -> A -> softmax -> svA
#define FL_NEXT   8   // write ego_next(raw) / te_next / Gnext(from regs)
#define FL_FIN    16  // out = (out + X_row + fn) / 3
#define FL_ACONST 32  // scores: A_old == 1 (skip record load if also FL_SVC)
#define FL_GN     128 // build Gnext = X_row * d  (X loaded, d from scores)

static inline int ceil_div(int a, int b) { return (a + b - 1) / b; }

static __device__ inline float bf2f(unsigned short u) {
    return __uint_as_float(((unsigned int)u) << 16);
}
static __device__ inline float blo(unsigned int u) {
    return __uint_as_float(u << 16);
}
static __device__ inline float bhi(unsigned int u) {
    return __uint_as_float(u & 0xffff0000u);
}
static __device__ inline unsigned short f2bf(float f) {
    unsigned int x = __float_as_uint(f);
    x += 0x7fffu + ((x >> 16) & 1u);
    return (unsigned short)(x >> 16);
}
static __device__ inline unsigned short f2h(float f) {
    _Float16 h = (_Float16)f;
    return __builtin_bit_cast(unsigned short, h);
}
static __device__ inline float h2f(unsigned short u) {
    return (float)__builtin_bit_cast(_Float16, u);
}

// packed bf16x2 dot: c += a.lo*b.lo + a.hi*b.hi (hw v_dot2_f32_bf16 if present)
#if __has_builtin(__builtin_amdgcn_fdot2_f32_bf16)
typedef __bf16 bf16x2_t __attribute__((ext_vector_type(2)));
static __device__ inline float dot2bf(unsigned int a, unsigned int b, float c) {
    return __builtin_amdgcn_fdot2_f32_bf16(__builtin_bit_cast(bf16x2_t, a),
                                           __builtin_bit_cast(bf16x2_t, b), c, false);
}
#else
static __device__ inline float dot2bf(unsigned int a, unsigned int b, float c) {
    return c + blo(a) * blo(b) + bhi(a) * bhi(b);
}
#endif

// ---- padded-bucket CSR build (once per launch) ----
__global__ void k_binscat(const int* __restrict__ head, const int* __restrict__ tail,
                          int* __restrict__ cursor, int* __restrict__ bin) {
    __shared__ int cnt[NBLK];
    __shared__ int chunk[NBLK];
    int tid = threadIdx.x;
    for (int i = tid; i < NBLK; i += 256) cnt[i] = 0;
    __syncthreads();
    int e0 = blockIdx.x * EPB;
    int e1 = min(e0 + EPB, NNZ_);
    for (int e = e0 + tid; e < e1; e += 256)
        atomicAdd(&cnt[head[e] >> 8], 1);
    __syncthreads();
    for (int i = tid; i < NBLK; i += 256) {
        chunk[i] = cnt[i] ? (i * BINC + atomicAdd(&cursor[i], cnt[i])) : 0;
        cnt[i] = 0;   // reuse as local cursor
    }
    __syncthreads();
    for (int e = e0 + tid; e < e1; e += 256) {
        int h = head[e], t = tail[e];
        int b = h >> 8;
        int off = atomicAdd(&cnt[b], 1);
        bin[chunk[b] + off] = t | ((h & 255) << 20);   // t < 2^17, hl < 2^8
    }
}

__global__ void k_bucket(const int* __restrict__ bin, const int* __restrict__ cursor,
                         int2* __restrict__ row_se, float4* __restrict__ d4a,
                         int* __restrict__ csr_tail) {
    __shared__ int deg[256];
    __shared__ int sh[256];
    __shared__ int cur[256];
    int tid = threadIdx.x;
    int b = blockIdx.x;
    int n0 = b << 8;
    int e0 = b * BINC, e1 = e0 + cursor[b];
    deg[tid] = 0;
    __syncthreads();
    for (int e = e0 + tid; e < e1; e += 256)
        atomicAdd(&deg[bin[e] >> 20], 1);
    __syncthreads();
    int myDeg = deg[tid];
    sh[tid] = myDeg;
    __syncthreads();
    for (int off = 1; off < 256; off <<= 1) {
        int u = 0;
        if (tid >= off) u = sh[tid - off];
        __syncthreads();
        sh[tid] += u;
        __syncthreads();
    }
    int loff = sh[tid] - myDeg;   // exclusive local offset
    int start = b * BINC + loff;  // csr window shares the BINC stride
    int n = n0 + tid;
    if (n < NN) {
        row_se[n] = make_int2(start, start + myDeg);
        float dd = (myDeg > 0) ? 2.0f / sqrtf((float)myDeg) : 0.0f;
        d4a[n] = make_float4(dd, dd, dd, dd);
    }
    cur[tid] = start;
    __syncthreads();
    for (int e = e0 + tid; e < e1; e += 256) {
        int p = bin[e];
        int pos = atomicAdd(&cur[p >> 20], 1);
        csr_tail[pos] = p & 0xFFFFF;
    }
}

// ego = raw bf16; te = tanh(l2norm chunk16); G0 = ego*d0; out = ego f32.
__global__ void k_init(const float* __restrict__ eu, const float* __restrict__ ei,
                       const float* __restrict__ d4a,   // viewed as float[NN*4]
                       unsigned short* __restrict__ ego, unsigned short* __restrict__ te,
                       unsigned short* __restrict__ G0, float* __restrict__ out) {
    int i = blockIdx.x * 256 + threadIdx.x;
    if (i >= NN * DIM_) return;
    float v = (i < NUSER * DIM_) ? eu[i] : ei[i - NUSER * DIM_];
    out[i] = v;
    ego[i] = f2bf(v);
    G0[i] = f2bf(v * d4a[i >> 4]);   // i>>4 == n*4 + f
    float s = v * v;
    s += __shfl_xor(s, 1); s += __shfl_xor(s, 2);
    s += __shfl_xor(s, 4); s += __shfl_xor(s, 8);
    float nrm = v / fmaxf(sqrtf(s), 1e-12f);
    float ex = __expf(2.0f * nrm);
    te[i] = f2bf((ex - 1.0f) / (ex + 1.0f));
}

#define QRED(a) { a += __shfl_xor(a, 8); a += __shfl_xor(a, 16); a += __shfl_xor(a, 32); }

// ---- fused walk + scores body ----
// lane = 8q + l8: q = edge slot (0..7), l8 = dim octet (dims 8*l8..8*l8+7,
// all within factor f2 = l8>>1). One uint4 (16 B) load covers a lane's dims.
// NJ = chunk0 depth in 8-edge groups (1 or 2); NJ==2 arm also handles deg>16.
template<int FLAGS, int NJ>
static __device__ __forceinline__ void iter_body(
    int n, int lane, int q, int l8, int f2, int r0, int r1,
    unsigned int* __restrict__ svA,
    const unsigned short* __restrict__ G,
    const unsigned short* __restrict__ te,
    const int* __restrict__ csr_tail,
    float* __restrict__ out,
    const unsigned short* __restrict__ X,   // raw row source (GN / FIN)
    unsigned short* __restrict__ Gn,
    unsigned short* __restrict__ egon, unsigned short* __restrict__ ten)
{
    constexpr bool needRec = !(FLAGS & FL_SVC) || ((FLAGS & FL_SC) && !(FLAGS & FL_ACONST));
    int deg = r1 - r0;
    float a0 = 0.f, a1 = 0.f, a2 = 0.f, a3 = 0.f;
    float a4 = 0.f, a5 = 0.f, a6 = 0.f, a7 = 0.f;

    // ---- chunk 0: edges r0 + q + 8j, j=0..NJ-1 (te cached for scores) ----
    int ct[NJ]; float cw[NJ]; unsigned int cr[NJ]; uint4 cv[NJ];
#pragma unroll
    for (int j = 0; j < NJ; ++j) {
        int i = r0 + q + 8 * j;
        bool v = (i < r1);
        int ic = v ? i : r0;
        int t = csr_tail[ic];
        ct[j] = v ? t : 0;            // padding holes are uninitialized
        if (needRec) cr[j] = svA[ic * 4 + f2];
        float w;
        if (FLAGS & FL_SVC) w = 1.0f;
        else w = bf2f((unsigned short)(cr[j] & 0xffffu));
        cw[j] = v ? w : 0.f;
    }
#pragma unroll
    for (int j = 0; j < NJ; ++j) {
        if (FLAGS & FL_SC)
            cv[j] = *(const uint4*)(te + ct[j] * 64 + 8 * l8);
    }
#pragma unroll
    for (int j = 0; j < NJ; ++j) {
        uint4 gu = *(const uint4*)(G + ct[j] * 64 + 8 * l8);
        float w = cw[j];
        a0 += w * blo(gu.x); a1 += w * bhi(gu.x);
        a2 += w * blo(gu.y); a3 += w * bhi(gu.y);
        a4 += w * blo(gu.z); a5 += w * bhi(gu.z);
        a6 += w * blo(gu.w); a7 += w * bhi(gu.w);
    }

    // ---- remainder (deg > 16), NJ==2 arm only: 8 edges per step ----
    if (NJ == 2) {
        for (int base = r0 + 16; base < r1; base += 8) {
            int i = base + q;
            bool v = (i < r1);
            int ic = v ? i : r0;
            int t = csr_tail[ic];
            t = v ? t : 0;
            float w;
            if (FLAGS & FL_SVC) w = 1.0f;
            else w = bf2f((unsigned short)(svA[ic * 4 + f2] & 0xffffu));
            w = v ? w : 0.f;
            uint4 gu = *(const uint4*)(G + t * 64 + 8 * l8);
            a0 += w * blo(gu.x); a1 += w * bhi(gu.x);
            a2 += w * blo(gu.y); a3 += w * bhi(gu.y);
            a4 += w * blo(gu.z); a5 += w * bhi(gu.z);
            a6 += w * blo(gu.w); a7 += w * bhi(gu.w);
        }
    }

    // reduce over the 8 edge slots (lane bits 3,4,5)
    QRED(a0) QRED(a1) QRED(a2) QRED(a3)
    QRED(a4) QRED(a5) QRED(a6) QRED(a7)

    // l2 norm over the 16-dim factor chunk (pair l8^1 holds the other 8 dims)
    float s = a0 * a0 + a1 * a1 + a2 * a2 + a3 * a3
            + a4 * a4 + a5 * a5 + a6 * a6 + a7 * a7;
    s += __shfl_xor(s, 1);
    float inv = 1.0f / fmaxf(sqrtf(s), 1e-12f);
    float f0 = a0 * inv, f1 = a1 * inv, f2v = a2 * inv, f3 = a3 * inv;
    float f4 = a4 * inv, f5 = a5 * inv, f6 = a6 * inv, f7 = a7 * inv;

    // epilogue dim ownership: lane (q,l8) writes dim k = 8*l8 + q (bijective)
    int k = 8 * l8 + q;
    float y = 0.f;
    if (FLAGS & (FL_NEXT | FL_FIN)) {
        y = (q & 4) ? ((q & 2) ? ((q & 1) ? f7 : f6) : ((q & 1) ? f5 : f4))
                    : ((q & 2) ? ((q & 1) ? f3 : f2v) : ((q & 1) ? f1 : f0));
        int base = n * 64 + k;
        if (FLAGS & FL_FIN) {
            // out holds init; X row n holds bf16 fn1 -> 3-term mean
            out[base] = (out[base] + bf2f(X[base]) + y) * (1.0f / 3.0f);
        }
        if (FLAGS & FL_NEXT) {
            egon[base] = f2bf(y);
            float e2 = __expf(2.0f * y);
            ten[base] = f2bf((e2 - 1.0f) / (e2 + 1.0f));
        }
    }

    float accs = 0.f;   // rowsum of svals for factor f2 (per q-subset, then QRED)
    if (FLAGS & FL_SC) {
        // pack fn: 4 bf16x2 words covering the lane's 8 dims
        unsigned int p0 = ((unsigned int)f2bf(f1) << 16) | f2bf(f0);
        unsigned int p1 = ((unsigned int)f2bf(f3) << 16) | f2bf(f2v);
        unsigned int p2 = ((unsigned int)f2bf(f5) << 16) | f2bf(f4);
        unsigned int p3 = ((unsigned int)f2bf(f7) << 16) | f2bf(f6);
        // cached chunk 0: pure register compute
#pragma unroll
        for (int j = 0; j < NJ; ++j) {
            int i = r0 + q + 8 * j;
            bool v = (i < r1);
            float dot = dot2bf(cv[j].w, p3, dot2bf(cv[j].z, p2,
                        dot2bf(cv[j].y, p1, dot2bf(cv[j].x, p0, 0.0f))));
            dot += __shfl_xor(dot, 1);            // full 16-dim factor dot
            float a = (FLAGS & FL_ACONST) ? 1.0f : h2f((unsigned short)(cr[j] >> 16));
            a += dot;
            float ex = __expf(a);
            float sum = ex;
            sum += __shfl_xor(sum, 2); sum += __shfl_xor(sum, 4);  // over 4 factors
            float sv = ex / sum;
            if (v && (l8 & 1) == 0)
                svA[i * 4 + f2] = (unsigned int)f2bf(sv) | ((unsigned int)f2h(a) << 16);
            accs += v ? sv : 0.f;
        }
        // remainder chunks: re-gather tails/records -> te
        if (NJ == 2) {
            for (int base = r0 + 16; base < r1; base += 8) {
                int i = base + q;
                bool v = (i < r1);
                int ic = v ? i : r0;
                int t = csr_tail[ic];
                t = v ? t : 0;
                float aj = 1.0f;
                if (!(FLAGS & FL_ACONST))
                    aj = h2f((unsigned short)(svA[ic * 4 + f2] >> 16));
                uint4 tv = *(const uint4*)(te + t * 64 + 8 * l8);
                float dot = dot2bf(tv.w, p3, dot2bf(tv.z, p2,
                            dot2bf(tv.y, p1, dot2bf(tv.x, p0, 0.0f))));
                dot += __shfl_xor(dot, 1);
                float a = aj + dot;
                float ex = __expf(a);
                float sum = ex;
                sum += __shfl_xor(sum, 2); sum += __shfl_xor(sum, 4);
                float sv = ex / sum;
                if (v && (l8 & 1) == 0)
                    svA[i * 4 + f2] = (unsigned int)f2bf(sv) | ((unsigned int)f2h(a) << 16);
                accs += v ? sv : 0.f;
            }
        }
        QRED(accs)   // total rowsum for factor f2, replicated on all lanes
    }

    if (FLAGS & (FL_GN | FL_NEXT)) {
        // d for the OUTPUT dim's factor fo = k>>4; accs for factor g lives on
        // lane l8 = 2g (q = 0).
        int fo = k >> 4;
        float av = __shfl(accs, 2 * fo);
        float d = (av > 0.f) ? 1.0f / sqrtf(fmaxf(av, 1e-12f)) : 0.f;
        int base = n * 64 + k;
        float src = (FLAGS & FL_NEXT) ? y : bf2f(X[base]);
        Gn[base] = f2bf(src * d);
    }
}

// dispatcher: one wave per node; deg is wave-uniform (SGPR) -> scalar branch
template<int FLAGS>
__global__ void k_iter(unsigned int* __restrict__ svA,
                       const unsigned short* __restrict__ G,
                       const unsigned short* __restrict__ te,
                       const int2* __restrict__ row_se, const int* __restrict__ csr_tail,
                       float* __restrict__ out,
                       const unsigned short* __restrict__ X,
                       unsigned short* __restrict__ Gn,
                       unsigned short* __restrict__ egon, unsigned short* __restrict__ ten) {
    int n = (blockIdx.x * 256 + threadIdx.x) >> 6;
    if (n >= NN) return;
    int lane = threadIdx.x & 63;
    int q = lane >> 3;
    int l8 = lane & 7;
    int f2 = l8 >> 1;
    int2 se = row_se[n];
    int r0 = __builtin_amdgcn_readfirstlane(se.x);
    int r1 = __builtin_amdgcn_readfirstlane(se.y);
    if (r1 - r0 <= 8)
        iter_body<FLAGS, 1>(n, lane, q, l8, f2, r0, r1, svA, G, te,
                            csr_tail, out, X, Gn, egon, ten);
    else
        iter_body<FLAGS, 2>(n, lane, q, l8, f2, r0, r1, svA, G, te,
                            csr_tail, out, X, Gn, egon, ten);
}

extern "C" void kernel_launch(void* const* d_in, const int* in_sizes, int n_in,
                              void* d_out, int out_size, void* d_ws, size_t ws_size,
                              hipStream_t stream) {
    const float* eu = (const float*)d_in[0];
    const float* ei = (const float*)d_in[1];
    const int* head = (const int*)d_in[2];
    const int* tail = (const int*)d_in[3];
    float* out = (float*)d_out;   // holds init until it3's 3-term mean (FL_FIN)

    // workspace layout — ~111 MB (16B-aligned first).
    // svA = merged per-edge record (NPAD*4 uints). bin (6.4 MB) aliases svA
    // (bin dead after k_bucket; svA first written in it0's scores phase).
    unsigned int* svA = (unsigned int*)d_ws;                // 25.6 MB (NPAD*4)
    float* d4a = (float*)(svA + (size_t)NPAD * 4);          // 1.6 MB (it0 seed only)
    unsigned short* ego_a = (unsigned short*)(d4a + (size_t)NN * 4);  // 12.8 MB (raw)
    unsigned short* te_a  = ego_a + (size_t)NN * DIM_;      // 12.8 MB
    unsigned short* ego_b = te_a + (size_t)NN * DIM_;       // 12.8 MB (raw fn1)
    unsigned short* te_b  = ego_b + (size_t)NN * DIM_;      // 12.8 MB
    unsigned short* Ga    = te_b + (size_t)NN * DIM_;       // 12.8 MB
    unsigned short* Gb    = Ga + (size_t)NN * DIM_;         // 12.8 MB
    int* csr_tail = (int*)(Gb + (size_t)NN * DIM_);         // 6.4 MB (NPAD)
    int2* row_se = (int2*)(csr_tail + (size_t)NPAD);        // 0.8 MB
    int* cursor = (int*)(row_se + NN);                      // NBLK
    int* bin = (int*)svA;                                   // 6.4 MB alias

    const int node_blocks = ceil_div(NN * DIM_, 256);      // 25000
    const int wave_blocks = ceil_div(NN * 64, 256);        // 25000

    // padded-bucket CSR build + d0 = 2/sqrt(deg) seed (rowsum0 = 0.25*deg)
    hipMemsetAsync(cursor, 0, NBLK * sizeof(int), stream);
    k_binscat<<<NBLK, 256, 0, stream>>>(head, tail, cursor, bin);
    k_bucket<<<NBLK, 256, 0, stream>>>(bin, cursor, row_se, (float4*)d4a, csr_tail);

    // init AFTER csr build: ego_a raw, te_a, G0 = ego_a*d0 -> Ga, out = init
    k_init<<<node_blocks, 256, 0, stream>>>(eu, ei, d4a, ego_a, te_a, Ga, out);

    // it0: walk Ga (uniform weights cancel in norm); scores vs te_a:
    // A1 = 1 + s0, svals_1 -> svA (packed); epilogue G1 = ego_a*d1 -> Gb.
    k_iter<FL_SVC | FL_SC | FL_ACONST | FL_GN><<<wave_blocks, 256, 0, stream>>>(
        svA, Ga, te_a, row_se, csr_tail, out, ego_a, Gb, ego_b, te_b);

    // it1: walk Gb with svals_1; fn1 -> ego_b(raw) + te_b; scores vs te_a:
    // A2 = A1 + s1, svals_2 -> svA; epilogue G2 = fn1*d2 -> Ga.
    k_iter<FL_SC | FL_NEXT><<<wave_blocks, 256, 0, stream>>>(
        svA, Gb, te_a, row_se, csr_tail, out, ego_a, Ga, ego_b, te_b);

    // it2: walk Ga with svals_2; scores vs te_b: A3 = A2 + s2, svals_3 -> svA;
    // epilogue G3 = ego_b*d3 -> Gb.
    k_iter<FL_SC | FL_GN><<<wave_blocks, 256, 0, stream>>>(
        svA, Ga, te_b, row_se, csr_tail, out, ego_b, Gb, ego_b, te_b);

    // it3: walk Gb with svals_3; no scores; out = (init + fn1 + fn3)/3.
    k_iter<FL_FIN><<<wave_blocks, 256, 0, stream>>>(
        svA, Gb, te_b, row_se, csr_tail, out, ego_b, Ga, ego_b, te_b);
}